// Round 4
// baseline (412.028 us; speedup 1.0000x reference)
//
#include <hip/hip_runtime.h>
#include <hip/hip_bf16.h>

typedef short bf16x8 __attribute__((ext_vector_type(8)));
typedef float f32x16 __attribute__((ext_vector_type(16)));
typedef float f32x4v __attribute__((ext_vector_type(4)));

#define GN 8192
#define GD 128
#define KSPLIT 8

// ws layout:
// [0, 32768)             : s (fp32, 8192) = rsqrt(rowsum)
// [32768, +2359296)      : yp packed bf16: [128 kb][128 col][72 bf16]  (y = (Sx)W^T)
// [2392064, +134217728)  : adj_bf16 row-major, pre-scaled by s_i  (128 MB)

// Pass 1: rowsum -> s_i, and rewrite row as bf16 * s_i.
__global__ __launch_bounds__(256) void k_rowcvt(const float* __restrict__ adj,
                                                float* __restrict__ s,
                                                __hip_bfloat16* __restrict__ adjb) {
  const int row = blockIdx.x;
  const int t = threadIdx.x;
  const f32x4v* p = (const f32x4v*)(adj + (size_t)row * GN);
  f32x4v v[8];
  float acc = 0.f;
#pragma unroll
  for (int i = 0; i < 8; ++i) {
    v[i] = __builtin_nontemporal_load(p + t + i * 256);
    acc += (v[i].x + v[i].y) + (v[i].z + v[i].w);
  }
#pragma unroll
  for (int off = 32; off > 0; off >>= 1) acc += __shfl_down(acc, off, 64);
  __shared__ float red[4];
  __shared__ float sbc;
  if ((t & 63) == 0) red[t >> 6] = acc;
  __syncthreads();
  if (t == 0) {
    float tot = (red[0] + red[1]) + (red[2] + red[3]);
    float sc = (tot > 0.f) ? rsqrtf(tot) : 0.f;
    sbc = sc;
    s[row] = sc;
  }
  __syncthreads();
  const float sc = sbc;
  __hip_bfloat16* orow = adjb + (size_t)row * GN;
#pragma unroll
  for (int i = 0; i < 8; ++i) {
    __hip_bfloat16 hb[4];
    hb[0] = __float2bfloat16(v[i].x * sc);
    hb[1] = __float2bfloat16(v[i].y * sc);
    hb[2] = __float2bfloat16(v[i].z * sc);
    hb[3] = __float2bfloat16(v[i].w * sc);
    *(uint2*)(orow + (size_t)(t + i * 256) * 4) = *(uint2*)hb;
  }
}

// y = (S x) @ W^T, packed into B-operand layout: yp[kb][c=out-col][kk] stride 72.
// One block per 64 k-rows. MFMA 32x32x16.
__global__ __launch_bounds__(256) void k_packy(const float* __restrict__ x,
                                               const float* __restrict__ s,
                                               const float* __restrict__ W,
                                               __hip_bfloat16* __restrict__ yp) {
  __shared__ __align__(16) __hip_bfloat16 Xs[64 * 136];
  __shared__ __align__(16) __hip_bfloat16 Ws[128 * 136];
  __shared__ __align__(16) __hip_bfloat16 Yp[128 * 72];
  __shared__ float sv[64];
  const int kb = blockIdx.x;
  const int t = threadIdx.x;
  if (t < 64) sv[t] = s[kb * 64 + t];
  __syncthreads();
  // stage Xs = bf16(s_k * x[k][:])  (64 rows x 128)
  const float4* xp = (const float4*)(x + (size_t)kb * 64 * GD);
#pragma unroll
  for (int j = 0; j < 8; ++j) {
    int i = t + j * 256;            // 2048 float4 = 64 rows x 32
    int r = i >> 5, c4 = i & 31;
    float4 v = xp[i];
    float sc = sv[r];
    __hip_bfloat16 hb[4];
    hb[0] = __float2bfloat16(v.x * sc);
    hb[1] = __float2bfloat16(v.y * sc);
    hb[2] = __float2bfloat16(v.z * sc);
    hb[3] = __float2bfloat16(v.w * sc);
    *(uint2*)(Xs + r * 136 + c4 * 4) = *(uint2*)hb;
  }
  // stage Ws (row-major W[o][d] IS the B-operand layout for W^T)
#pragma unroll
  for (int j = 0; j < 16; ++j) {
    int i = t + j * 256;            // 4096 float4 = 128 rows x 32
    int o = i >> 5, k4 = i & 31;
    float4 w = *(const float4*)(W + (size_t)o * GD + k4 * 4);
    __hip_bfloat16 hb[4];
    hb[0] = __float2bfloat16(w.x);
    hb[1] = __float2bfloat16(w.y);
    hb[2] = __float2bfloat16(w.z);
    hb[3] = __float2bfloat16(w.w);
    *(uint2*)(Ws + o * 136 + k4 * 4) = *(uint2*)hb;
  }
  __syncthreads();
  const int lane = t & 63;
  const int wave = t >> 6;
  const int mtile = wave & 1;          // rows mtile*32..+31
  const int n0 = (wave >> 1) * 2;      // two ntiles: n0, n0+1
  const int koff = (lane >> 5) * 8;
  const int arow = mtile * 32 + (lane & 31);
  f32x16 acc0, acc1;
#pragma unroll
  for (int i = 0; i < 16; ++i) { acc0[i] = 0.f; acc1[i] = 0.f; }
#pragma unroll
  for (int kk = 0; kk < 128; kk += 16) {
    bf16x8 af = *(const bf16x8*)(Xs + arow * 136 + kk + koff);
    bf16x8 b0 = *(const bf16x8*)(Ws + (n0 * 32 + (lane & 31)) * 136 + kk + koff);
    bf16x8 b1 = *(const bf16x8*)(Ws + ((n0 + 1) * 32 + (lane & 31)) * 136 + kk + koff);
    acc0 = __builtin_amdgcn_mfma_f32_32x32x16_bf16(af, b0, acc0, 0, 0, 0);
    acc1 = __builtin_amdgcn_mfma_f32_32x32x16_bf16(af, b1, acc1, 0, 0, 0);
  }
  // write y^T into packed LDS: Yp[c*72 + kk], c = out-col, kk = k within block
#pragma unroll
  for (int reg = 0; reg < 16; ++reg) {
    int kkl = mtile * 32 + (reg & 3) + 8 * (reg >> 2) + 4 * (lane >> 5);
    int c0 = n0 * 32 + (lane & 31);
    Yp[c0 * 72 + kkl] = __float2bfloat16(acc0[reg]);
    Yp[(c0 + 32) * 72 + kkl] = __float2bfloat16(acc1[reg]);
  }
  __syncthreads();
  // linear copy 18432 B to global
  const uint4* srcv = (const uint4*)Yp;
  uint4* dstv = (uint4*)((char*)yp + (size_t)kb * 18432);
  for (int i = t; i < 1152; i += 256) dstv[i] = srcv[i];
}

// bias init: out[i][o] = b[o]
__global__ __launch_bounds__(256) void k_bias(const float* __restrict__ b,
                                              float* __restrict__ out) {
  __shared__ float4 bs4[32];
  const int t = threadIdx.x;
  if (t < 32) bs4[t] = ((const float4*)b)[t];
  __syncthreads();
  const int row0 = blockIdx.x * 32;
#pragma unroll
  for (int j = 0; j < 4; ++j) {
    int i = t + j * 256;
    int r = i >> 5, c4 = i & 31;
    ((float4*)(out + (size_t)(row0 + r) * GD))[c4] = bs4[c4];
  }
}

// Main GEMM: out += adjb[:, slice] @ y[slice, :]  via fp32 atomics.
// BM=128 tile, 4 waves in 2x2, each wave 2x2 sub-tiles of 32x32.
__global__ __launch_bounds__(256, 2) void k_gemm(const __hip_bfloat16* __restrict__ adjb,
                                                 const __hip_bfloat16* __restrict__ yp,
                                                 float* __restrict__ out) {
  __shared__ __align__(16) __hip_bfloat16 Asm[128 * 72];
  __shared__ __align__(16) __hip_bfloat16 Bsm[128 * 72];
  const int mb = blockIdx.x;   // 0..63  (128-row tile)
  const int ks = blockIdx.y;   // 0..7   (K split, 1024 each)
  const int t = threadIdx.x;
  const int lane = t & 63;
  const int wave = t >> 6;
  const int wm = wave >> 1, wn = wave & 1;

  f32x16 acc00, acc01, acc10, acc11;
#pragma unroll
  for (int i = 0; i < 16; ++i) {
    acc00[i] = 0.f; acc01[i] = 0.f; acc10[i] = 0.f; acc11[i] = 0.f;
  }

  const int ar = t >> 1;             // A-stage: row 0..127
  const int ah = (t & 1) * 32;       // A-stage: 32-elem (64B) k-half
  const __hip_bfloat16* arow = adjb + (size_t)(mb * 128 + ar) * GN + ks * 1024 + ah;
  const char* bsrc_base = (const char*)yp + (size_t)(ks * 16) * 18432;

  const int a_lds_off = ar * 72 + ah;
  const int afrag_row = wm * 64 + (lane & 31);
  const int koff = (lane >> 5) * 8;
  const int bcol0 = wn * 64 + (lane & 31);

  for (int kt = 0; kt < 16; ++kt) {          // 16 iterations of BK=64
    // --- stage B tile: async DMA of pre-packed linear layout (18432 B) ---
    {
      const char* bg = bsrc_base + (size_t)kt * 18432;
#pragma unroll
      for (int c = 0; c < 5; ++c) {
        int chunk = wave + c * 4;
        if (chunk < 18) {
          __builtin_amdgcn_global_load_lds(
              (const __attribute__((address_space(1))) unsigned int*)(bg + chunk * 1024 + lane * 16),
              (__attribute__((address_space(3))) unsigned int*)((char*)Bsm + chunk * 1024),
              16, 0, 0);
        }
      }
    }
    // --- stage A tile (bf16, 64B/thread, padded rows) ---
    {
      const uint4* s4 = (const uint4*)(arow + (size_t)kt * 64);
      uint4 q0 = s4[0], q1 = s4[1], q2 = s4[2], q3 = s4[3];
      uint4* d = (uint4*)(Asm + a_lds_off);
      d[0] = q0; d[1] = q1; d[2] = q2; d[3] = q3;
    }
    __syncthreads();
#pragma unroll
    for (int kk = 0; kk < 64; kk += 16) {
      bf16x8 a0 = *(const bf16x8*)(Asm + afrag_row * 72 + kk + koff);
      bf16x8 a1 = *(const bf16x8*)(Asm + (afrag_row + 32) * 72 + kk + koff);
      bf16x8 b0 = *(const bf16x8*)(Bsm + bcol0 * 72 + kk + koff);
      bf16x8 b1 = *(const bf16x8*)(Bsm + (bcol0 + 32) * 72 + kk + koff);
      acc00 = __builtin_amdgcn_mfma_f32_32x32x16_bf16(a0, b0, acc00, 0, 0, 0);
      acc01 = __builtin_amdgcn_mfma_f32_32x32x16_bf16(a0, b1, acc01, 0, 0, 0);
      acc10 = __builtin_amdgcn_mfma_f32_32x32x16_bf16(a1, b0, acc10, 0, 0, 0);
      acc11 = __builtin_amdgcn_mfma_f32_32x32x16_bf16(a1, b1, acc11, 0, 0, 0);
    }
    __syncthreads();
  }

  float* ob = out + (size_t)(mb * 128) * GD;
#pragma unroll
  for (int reg = 0; reg < 16; ++reg) {
    int r0 = wm * 64 + (reg & 3) + 8 * (reg >> 2) + 4 * (lane >> 5);
    int c0 = wn * 64 + (lane & 31);
    atomicAdd(&ob[(size_t)r0 * GD + c0], acc00[reg]);
    atomicAdd(&ob[(size_t)r0 * GD + c0 + 32], acc01[reg]);
    atomicAdd(&ob[(size_t)(r0 + 32) * GD + c0], acc10[reg]);
    atomicAdd(&ob[(size_t)(r0 + 32) * GD + c0 + 32], acc11[reg]);
  }
}

extern "C" void kernel_launch(void* const* d_in, const int* in_sizes, int n_in,
                              void* d_out, int out_size, void* d_ws, size_t ws_size,
                              hipStream_t stream) {
  const float* x   = (const float*)d_in[0];
  const float* adj = (const float*)d_in[1];
  const float* W   = (const float*)d_in[2];
  const float* b   = (const float*)d_in[3];
  float* out = (float*)d_out;

  float* s = (float*)d_ws;
  __hip_bfloat16* yp   = (__hip_bfloat16*)((char*)d_ws + 32768);
  __hip_bfloat16* adjb = (__hip_bfloat16*)((char*)d_ws + 2392064);

  k_rowcvt<<<8192, 256, 0, stream>>>(adj, s, adjb);
  k_packy<<<128, 256, 0, stream>>>(x, s, W, yp);
  k_bias<<<256, 256, 0, stream>>>(b, out);
  k_gemm<<<dim3(64, KSPLIT), 256, 0, stream>>>(adjb, yp, out);
}

// Round 5
// 396.915 us; speedup vs baseline: 1.0381x; 1.0381x over previous
//
#include <hip/hip_runtime.h>
#include <hip/hip_bf16.h>

typedef short bf16x8 __attribute__((ext_vector_type(8)));
typedef float f32x16 __attribute__((ext_vector_type(16)));
typedef float f32x4v __attribute__((ext_vector_type(4)));

#define GN 8192
#define GD 128
#define KSPLIT 8

// ws layout:
// [0, 32768)             : s (fp32, 8192) = rsqrt(rowsum)
// [32768, +2359296)      : yp packed bf16: [128 kb][128 col][72 bf16]  (y = (Sx)W^T)
// [2392064, +134217728)  : adj_bf16 row-major, pre-scaled by s_i  (128 MB)
// [136609792, +33554432) : partials fp32 [8][8192][128]  (32 MB, L3-resident)

// Pass 1: rowsum -> s_i, and rewrite row as bf16 * s_i.
__global__ __launch_bounds__(256) void k_rowcvt(const float* __restrict__ adj,
                                                float* __restrict__ s,
                                                __hip_bfloat16* __restrict__ adjb) {
  const int row = blockIdx.x;
  const int t = threadIdx.x;
  const f32x4v* p = (const f32x4v*)(adj + (size_t)row * GN);
  f32x4v v[8];
  float acc = 0.f;
#pragma unroll
  for (int i = 0; i < 8; ++i) {
    v[i] = __builtin_nontemporal_load(p + t + i * 256);
    acc += (v[i].x + v[i].y) + (v[i].z + v[i].w);
  }
#pragma unroll
  for (int off = 32; off > 0; off >>= 1) acc += __shfl_down(acc, off, 64);
  __shared__ float red[4];
  __shared__ float sbc;
  if ((t & 63) == 0) red[t >> 6] = acc;
  __syncthreads();
  if (t == 0) {
    float tot = (red[0] + red[1]) + (red[2] + red[3]);
    float sc = (tot > 0.f) ? rsqrtf(tot) : 0.f;
    sbc = sc;
    s[row] = sc;
  }
  __syncthreads();
  const float sc = sbc;
  __hip_bfloat16* orow = adjb + (size_t)row * GN;
#pragma unroll
  for (int i = 0; i < 8; ++i) {
    __hip_bfloat16 hb[4];
    hb[0] = __float2bfloat16(v[i].x * sc);
    hb[1] = __float2bfloat16(v[i].y * sc);
    hb[2] = __float2bfloat16(v[i].z * sc);
    hb[3] = __float2bfloat16(v[i].w * sc);
    *(uint2*)(orow + (size_t)(t + i * 256) * 4) = *(uint2*)hb;
  }
}

// y = (S x) @ W^T, packed into B-operand layout: yp[kb][c=out-col][kk] stride 72.
__global__ __launch_bounds__(256) void k_packy(const float* __restrict__ x,
                                               const float* __restrict__ s,
                                               const float* __restrict__ W,
                                               __hip_bfloat16* __restrict__ yp) {
  __shared__ __align__(16) __hip_bfloat16 Xs[64 * 136];
  __shared__ __align__(16) __hip_bfloat16 Ws[128 * 136];
  __shared__ __align__(16) __hip_bfloat16 Yp[128 * 72];
  __shared__ float sv[64];
  const int kb = blockIdx.x;
  const int t = threadIdx.x;
  if (t < 64) sv[t] = s[kb * 64 + t];
  __syncthreads();
  const float4* xp = (const float4*)(x + (size_t)kb * 64 * GD);
#pragma unroll
  for (int j = 0; j < 8; ++j) {
    int i = t + j * 256;
    int r = i >> 5, c4 = i & 31;
    float4 v = xp[i];
    float sc = sv[r];
    __hip_bfloat16 hb[4];
    hb[0] = __float2bfloat16(v.x * sc);
    hb[1] = __float2bfloat16(v.y * sc);
    hb[2] = __float2bfloat16(v.z * sc);
    hb[3] = __float2bfloat16(v.w * sc);
    *(uint2*)(Xs + r * 136 + c4 * 4) = *(uint2*)hb;
  }
#pragma unroll
  for (int j = 0; j < 16; ++j) {
    int i = t + j * 256;
    int o = i >> 5, k4 = i & 31;
    float4 w = *(const float4*)(W + (size_t)o * GD + k4 * 4);
    __hip_bfloat16 hb[4];
    hb[0] = __float2bfloat16(w.x);
    hb[1] = __float2bfloat16(w.y);
    hb[2] = __float2bfloat16(w.z);
    hb[3] = __float2bfloat16(w.w);
    *(uint2*)(Ws + o * 136 + k4 * 4) = *(uint2*)hb;
  }
  __syncthreads();
  const int lane = t & 63;
  const int wave = t >> 6;
  const int mtile = wave & 1;
  const int n0 = (wave >> 1) * 2;
  const int koff = (lane >> 5) * 8;
  const int arow = mtile * 32 + (lane & 31);
  f32x16 acc0, acc1;
#pragma unroll
  for (int i = 0; i < 16; ++i) { acc0[i] = 0.f; acc1[i] = 0.f; }
#pragma unroll
  for (int kk = 0; kk < 128; kk += 16) {
    bf16x8 af = *(const bf16x8*)(Xs + arow * 136 + kk + koff);
    bf16x8 b0 = *(const bf16x8*)(Ws + (n0 * 32 + (lane & 31)) * 136 + kk + koff);
    bf16x8 b1 = *(const bf16x8*)(Ws + ((n0 + 1) * 32 + (lane & 31)) * 136 + kk + koff);
    acc0 = __builtin_amdgcn_mfma_f32_32x32x16_bf16(af, b0, acc0, 0, 0, 0);
    acc1 = __builtin_amdgcn_mfma_f32_32x32x16_bf16(af, b1, acc1, 0, 0, 0);
  }
#pragma unroll
  for (int reg = 0; reg < 16; ++reg) {
    int kkl = mtile * 32 + (reg & 3) + 8 * (reg >> 2) + 4 * (lane >> 5);
    int c0 = n0 * 32 + (lane & 31);
    Yp[c0 * 72 + kkl] = __float2bfloat16(acc0[reg]);
    Yp[(c0 + 32) * 72 + kkl] = __float2bfloat16(acc1[reg]);
  }
  __syncthreads();
  const uint4* srcv = (const uint4*)Yp;
  uint4* dstv = (uint4*)((char*)yp + (size_t)kb * 18432);
  for (int i = t; i < 1152; i += 256) dstv[i] = srcv[i];
}

// Main GEMM: part[ks] = adjb[:, slice] @ y[slice, :]
// BM=128 tile, 4 waves in 2x2, each wave 2x2 sub-tiles of 32x32.
__global__ __launch_bounds__(256, 2) void k_gemm(const __hip_bfloat16* __restrict__ adjb,
                                                 const __hip_bfloat16* __restrict__ yp,
                                                 float* __restrict__ part) {
  __shared__ __align__(16) __hip_bfloat16 Asm[128 * 72];
  __shared__ __align__(16) __hip_bfloat16 Bsm[128 * 72];
  const int mb = blockIdx.x;   // 0..63  (128-row tile)
  const int ks = blockIdx.y;   // 0..7   (K split, 1024 each)
  const int t = threadIdx.x;
  const int lane = t & 63;
  const int wave = t >> 6;
  const int wm = wave >> 1, wn = wave & 1;

  f32x16 acc00, acc01, acc10, acc11;
#pragma unroll
  for (int i = 0; i < 16; ++i) {
    acc00[i] = 0.f; acc01[i] = 0.f; acc10[i] = 0.f; acc11[i] = 0.f;
  }

  const int ar = t >> 1;
  const int ah = (t & 1) * 32;
  const __hip_bfloat16* arow = adjb + (size_t)(mb * 128 + ar) * GN + ks * 1024 + ah;
  const char* bsrc_base = (const char*)yp + (size_t)(ks * 16) * 18432;

  const int a_lds_off = ar * 72 + ah;
  const int afrag_row = wm * 64 + (lane & 31);
  const int koff = (lane >> 5) * 8;
  const int bcol0 = wn * 64 + (lane & 31);

  for (int kt = 0; kt < 16; ++kt) {
    {
      const char* bg = bsrc_base + (size_t)kt * 18432;
#pragma unroll
      for (int c = 0; c < 5; ++c) {
        int chunk = wave + c * 4;
        if (chunk < 18) {
          __builtin_amdgcn_global_load_lds(
              (const __attribute__((address_space(1))) unsigned int*)(bg + chunk * 1024 + lane * 16),
              (__attribute__((address_space(3))) unsigned int*)((char*)Bsm + chunk * 1024),
              16, 0, 0);
        }
      }
    }
    {
      const uint4* s4 = (const uint4*)(arow + (size_t)kt * 64);
      uint4 q0 = s4[0], q1 = s4[1], q2 = s4[2], q3 = s4[3];
      uint4* d = (uint4*)(Asm + a_lds_off);
      d[0] = q0; d[1] = q1; d[2] = q2; d[3] = q3;
    }
    __syncthreads();
#pragma unroll
    for (int kk = 0; kk < 64; kk += 16) {
      bf16x8 a0 = *(const bf16x8*)(Asm + afrag_row * 72 + kk + koff);
      bf16x8 a1 = *(const bf16x8*)(Asm + (afrag_row + 32) * 72 + kk + koff);
      bf16x8 b0 = *(const bf16x8*)(Bsm + bcol0 * 72 + kk + koff);
      bf16x8 b1 = *(const bf16x8*)(Bsm + (bcol0 + 32) * 72 + kk + koff);
      acc00 = __builtin_amdgcn_mfma_f32_32x32x16_bf16(a0, b0, acc00, 0, 0, 0);
      acc01 = __builtin_amdgcn_mfma_f32_32x32x16_bf16(a0, b1, acc01, 0, 0, 0);
      acc10 = __builtin_amdgcn_mfma_f32_32x32x16_bf16(a1, b0, acc10, 0, 0, 0);
      acc11 = __builtin_amdgcn_mfma_f32_32x32x16_bf16(a1, b1, acc11, 0, 0, 0);
    }
    __syncthreads();
  }

  float* pb = part + (size_t)ks * GN * GD + (size_t)(mb * 128) * GD;
#pragma unroll
  for (int reg = 0; reg < 16; ++reg) {
    int r0 = wm * 64 + (reg & 3) + 8 * (reg >> 2) + 4 * (lane >> 5);
    int c0 = wn * 64 + (lane & 31);
    pb[(size_t)r0 * GD + c0] = acc00[reg];
    pb[(size_t)r0 * GD + c0 + 32] = acc01[reg];
    pb[(size_t)(r0 + 32) * GD + c0] = acc10[reg];
    pb[(size_t)(r0 + 32) * GD + c0 + 32] = acc11[reg];
  }
}

// out = sum_ks part[ks] + bias
__global__ __launch_bounds__(256) void k_red(const float* __restrict__ part,
                                             const float* __restrict__ b,
                                             float* __restrict__ out) {
  __shared__ float4 bs4[32];
  const int t = threadIdx.x;
  if (t < 32) bs4[t] = ((const float4*)b)[t];
  __syncthreads();
  const int row0 = blockIdx.x * 32;
#pragma unroll
  for (int j = 0; j < 4; ++j) {
    int i = t + j * 256;               // 1024 float4 = 32 rows x 32
    int r = i >> 5, c4 = i & 31;
    size_t idx = (size_t)(row0 + r) * GD + c4 * 4;
    float4 a = bs4[c4];
#pragma unroll
    for (int ksl = 0; ksl < KSPLIT; ++ksl) {
      float4 p = *(const float4*)(part + idx + (size_t)ksl * GN * GD);
      a.x += p.x; a.y += p.y; a.z += p.z; a.w += p.w;
    }
    *(float4*)(out + idx) = a;
  }
}

extern "C" void kernel_launch(void* const* d_in, const int* in_sizes, int n_in,
                              void* d_out, int out_size, void* d_ws, size_t ws_size,
                              hipStream_t stream) {
  const float* x   = (const float*)d_in[0];
  const float* adj = (const float*)d_in[1];
  const float* W   = (const float*)d_in[2];
  const float* b   = (const float*)d_in[3];
  float* out = (float*)d_out;

  float* s = (float*)d_ws;
  __hip_bfloat16* yp   = (__hip_bfloat16*)((char*)d_ws + 32768);
  __hip_bfloat16* adjb = (__hip_bfloat16*)((char*)d_ws + 2392064);
  float* part = (float*)((char*)d_ws + 136609792);

  k_rowcvt<<<8192, 256, 0, stream>>>(adj, s, adjb);
  k_packy<<<128, 256, 0, stream>>>(x, s, W, yp);
  k_gemm<<<dim3(64, KSPLIT), 256, 0, stream>>>(adjb, yp, part);
  k_red<<<256, 256, 0, stream>>>(part, b, out);
}